// Round 5
// baseline (265.011 us; speedup 1.0000x reference)
//
#include <hip/hip_runtime.h>
#include <hip/hip_fp16.h>

// Fused Conv3d(3->16, 3x3x3, VALID) + bias + channel softmax + maxpool(4,4,4)/4.
// x: [512,3,16,32,32] f32, w: [16,3,3,3,3] f32, b: [16] f32 -> out [512,16,3,7,7] f32
//
// R15: R14 made VALU the dominant pipe (74% busy, MFMA 18%, HBM 16%). This
// round cuts per-site VALU fixed costs and hides staging latency structurally:
//  (a) 4 sites per block (same pd,ph; n = n0+128s; grid 2688): wa/tvi/pbi/
//      poolIdx/tail/staging-geometry setup computed once, reused 4x.
//  (b) cross-site prefetch: site s+1's 17 floats loaded to regs before site
//      s's MFMA main loop; converted+LDS-written after it (ping-pong buffers).
//  (c) log2(e) folded into weights+bias -> epilogue exp is raw v_exp_f32.
//  (d) per-tile epilogue store-index math hoisted to setup (poolIdx[7]).
// Main loop unchanged from R14: K=16 MFMA, 2 shift-copies, ds_read2_b32 per
// MFMA, fence-pinned double buffer. Epilogue DPP quad-max kept.

typedef _Float16 half4 __attribute__((ext_vector_type(4)));
typedef float f32x4 __attribute__((ext_vector_type(4)));
union H4 { int2 i; half4 h; };

template <int CTRL>
__device__ __forceinline__ float dpp_max(float x) {
  int xi = __builtin_bit_cast(int, x);
  int yi = __builtin_amdgcn_update_dpp(xi, xi, CTRL, 0xf, 0xf, false);
  return fmaxf(x, __builtin_bit_cast(float, yi));
}
// quad_perm ctrls: xor1 = [1,0,3,2] = 0xB1, xor2 = [2,3,0,1] = 0x4E

// Frag-ready weights for K=16, pre-scaled by log2(e): wsA[v][lane] = 4 halves
// A[c=lane&15][k=16v+4g+j], tap G = 4v+g, kw = j; zero for G>=27 or kw==3.
__global__ void wtrans(const float* __restrict__ w, int2* __restrict__ wsA) {
  int t = threadIdx.x;            // 448 threads: v = t>>6, lane = t&63
  if (t >= 448) return;
  int v = t >> 6, l = t & 63;
  int c = l & 15, g = l >> 4;
  int G = 4 * v + g;
  unsigned hh[4];
  for (int j = 0; j < 4; ++j) {
    float val = (G < 27 && j < 3) ? w[c * 81 + G * 3 + j] * 1.44269504088896f
                                  : 0.0f;
    __half h = __float2half(val);
    hh[j] = (unsigned)__half_as_ushort(h);
  }
  int2 o;
  o.x = (int)(hh[0] | (hh[1] << 16));
  o.y = (int)(hh[2] | (hh[3] << 16));
  wsA[v * 64 + l] = o;
}

__global__ __launch_bounds__(256, 4) void conv_sm_pool(
    const float* __restrict__ x, const int2* __restrict__ wsA,
    const float* __restrict__ b, float* __restrict__ out) {
  // Two ping-pong tile buffers. Each: 2 shifted copies of the 3456-half
  // stream (copy1 = shift-1-half) at int offsets 0 and 1736. Rows unpadded.
  // Gather: half-window Q..Q+3 -> copy Q&1, int index Q>>1 via ds_read2_b32.
  // Pool buffer [dd*4+dh][pw][c] aliases the CURRENT buffer post-main.
  __shared__ int lds[2][3472];

  const int tid = threadIdx.x;
  const int blk = blockIdx.x;                 // 2688 blocks
  const int n0 = blk / 21, rr = blk % 21, pd = rr / 7, ph = rr % 7;

  const int lane = tid & 63;
  const int dd = tid >> 6;            // wave = one dd slice (0..3)
  const int l15 = lane & 15, g = lane >> 4;

  // ---- once-per-block setup ----
  H4 wa[7];
#pragma unroll
  for (int v = 0; v < 7; ++v) wa[v].i = wsA[v * 64 + lane];

  float4 b4 = *reinterpret_cast<const float4*>(b + 4 * g);
  f32x4 binit;
  binit[0] = b4.x * 1.44269504088896f;
  binit[1] = b4.y * 1.44269504088896f;
  binit[2] = b4.z * 1.44269504088896f;
  binit[3] = b4.w * 1.44269504088896f;

  // tap-group int offsets: T = cin*576 + kd*96 + kh*16 for G = 4v+g (clamped)
  int tvi[7];
#pragma unroll
  for (int v = 0; v < 7; ++v) {
    int G = 4 * v + g;
    if (G > 26) G = 26;
    int cin = G / 9, r = G % 9;
    tvi[v] = cin * 576 + (r / 3) * 96 + (r % 3) * 16;
  }

  // position bases: P = dd*192 + dh*32 + wp (halves); pbi = (P>>1)+(P&1)*1736
  // and pool-store indices (hoisted from the epilogue).
  int pbi[7], poolIdx[7];
#pragma unroll
  for (int tl = 0; tl < 7; ++tl) {
    int rem = tl * 16;
    int dh0 = rem / 28, rem28 = rem % 28;
    int bump = (rem28 + l15) >= 28 ? 1 : 0;
    int wp = rem28 + l15 - 28 * bump;
    int dh = dh0 + bump;
    int P = dd * 192 + dh * 32 + wp;
    pbi[tl] = (P >> 1) + (P & 1) * 1736;
    poolIdx[tl] = (((dd * 4 + dh) * 7 + (wp >> 2)) << 4) + 4 * g;
  }
  const bool poolWr = (l15 & 3) == 0;

  // staging geometry (tid<216): one (row,seg) per thread
  const int row = tid >> 1, seg = tid & 1;    // row = cin*36 + ld*6 + lh
  const int s_lh = row % 6, s_t2 = row / 6;
  const int s_ld = s_t2 % 6, s_cin = s_t2 / 6;
  const int goff = ((s_cin * 16 + s_ld) * 32 + s_lh) * 32 + seg * 16;
  const int li = row * 16 + seg * 8;
  const bool stager = (tid < 216);

  // tail geometry (tid<224)
  const int tIdx = tid >> 1, th = tid & 1;
  const int tc = tIdx / 7, tpw = tIdx % 7;
  const int tailBase = ((th * 8) * 7 + tpw) * 16 + tc;   // +112 per slot
  const size_t outOff = (size_t)(tc * 3 + pd) * 49 + (size_t)ph * 7 + tpw;

  const float* xbase = x + (size_t)n0 * 49152
                     + (size_t)(4 * pd) * 1024 + (size_t)(4 * ph) * 32;

  float4 pf0, pf1, pf2, pf3;
  float pfx;
  auto issue_load = [&](const float* src) {
    pf0 = *reinterpret_cast<const float4*>(src);
    pf1 = *reinterpret_cast<const float4*>(src + 4);
    pf2 = *reinterpret_cast<const float4*>(src + 8);
    pf3 = *reinterpret_cast<const float4*>(src + 12);
    pfx = src[16];
  };
  auto cvt_write = [&](int* buf) {
    int c[8];
    __half2 h;
    h = __float22half2_rn(make_float2(pf0.x, pf0.y)); c[0] = *reinterpret_cast<int*>(&h);
    h = __float22half2_rn(make_float2(pf0.z, pf0.w)); c[1] = *reinterpret_cast<int*>(&h);
    h = __float22half2_rn(make_float2(pf1.x, pf1.y)); c[2] = *reinterpret_cast<int*>(&h);
    h = __float22half2_rn(make_float2(pf1.z, pf1.w)); c[3] = *reinterpret_cast<int*>(&h);
    h = __float22half2_rn(make_float2(pf2.x, pf2.y)); c[4] = *reinterpret_cast<int*>(&h);
    h = __float22half2_rn(make_float2(pf2.z, pf2.w)); c[5] = *reinterpret_cast<int*>(&h);
    h = __float22half2_rn(make_float2(pf3.x, pf3.y)); c[6] = *reinterpret_cast<int*>(&h);
    h = __float22half2_rn(make_float2(pf3.z, pf3.w)); c[7] = *reinterpret_cast<int*>(&h);
    int eh = (int)__half_as_ushort(__float2half(pfx));
    int sft[8];
#pragma unroll
    for (int k = 0; k < 7; ++k) sft[k] = __builtin_amdgcn_alignbit(c[k + 1], c[k], 16);
    sft[7] = __builtin_amdgcn_alignbit(eh, c[7], 16);
    int4 w0; w0.x = c[0]; w0.y = c[1]; w0.z = c[2]; w0.w = c[3];
    int4 w1; w1.x = c[4]; w1.y = c[5]; w1.z = c[6]; w1.w = c[7];
    *reinterpret_cast<int4*>(&buf[li])     = w0;
    *reinterpret_cast<int4*>(&buf[li + 4]) = w1;
    int4 w2; w2.x = sft[0]; w2.y = sft[1]; w2.z = sft[2]; w2.w = sft[3];
    int4 w3; w3.x = sft[4]; w3.y = sft[5]; w3.z = sft[6]; w3.w = sft[7];
    *reinterpret_cast<int4*>(&buf[1736 + li])     = w2;
    *reinterpret_cast<int4*>(&buf[1736 + li + 4]) = w3;
  };

  // ---- prologue: stage site0, issue loads for site1 ----
  if (stager) {
    issue_load(xbase + goff);
    cvt_write(&lds[0][0]);
    issue_load(xbase + 6291456 + goff);   // n stride 128 sites = 128*49152
  }
  __syncthreads();

  // ---- 4 sites, ping-pong ----
#pragma unroll
  for (int s = 0; s < 4; ++s) {
    const int cur = s & 1;
    const int* Bp = &lds[cur][0];

    f32x4 acc[7];
#pragma unroll
    for (int tl = 0; tl < 7; ++tl) acc[tl] = binit;

    // main: 7 K-windows x 7 N-tiles, double-buffered, fence-pinned
    H4 bfA[7], bfB[7];
#pragma unroll
    for (int tl = 0; tl < 7; ++tl) {
      const int* p = &Bp[pbi[tl] + tvi[0]];
      bfA[tl].i.x = p[0]; bfA[tl].i.y = p[1];
    }
    __builtin_amdgcn_sched_barrier(0);
#pragma unroll
    for (int vv = 0; vv < 3; ++vv) {
      const int v0 = 2 * vv, v1 = 2 * vv + 1, v2 = 2 * vv + 2;
#pragma unroll
      for (int tl = 0; tl < 7; ++tl) {
        const int* p = &Bp[pbi[tl] + tvi[v1]];
        bfB[tl].i.x = p[0]; bfB[tl].i.y = p[1];
      }
      __builtin_amdgcn_sched_barrier(0);
#pragma unroll
      for (int tl = 0; tl < 7; ++tl)
        acc[tl] = __builtin_amdgcn_mfma_f32_16x16x16f16(wa[v0].h, bfA[tl].h, acc[tl], 0, 0, 0);
      __builtin_amdgcn_sched_barrier(0);
#pragma unroll
      for (int tl = 0; tl < 7; ++tl) {
        const int* p = &Bp[pbi[tl] + tvi[v2]];
        bfA[tl].i.x = p[0]; bfA[tl].i.y = p[1];
      }
      __builtin_amdgcn_sched_barrier(0);
#pragma unroll
      for (int tl = 0; tl < 7; ++tl)
        acc[tl] = __builtin_amdgcn_mfma_f32_16x16x16f16(wa[v1].h, bfB[tl].h, acc[tl], 0, 0, 0);
      __builtin_amdgcn_sched_barrier(0);
    }
#pragma unroll
    for (int tl = 0; tl < 7; ++tl)
      acc[tl] = __builtin_amdgcn_mfma_f32_16x16x16f16(wa[6].h, bfA[tl].h, acc[tl], 0, 0, 0);

    // publish next site's tile into the other buffer; issue loads for s+2
    if (s < 3 && stager) cvt_write(&lds[cur ^ 1][0]);
    if (s < 2 && stager) issue_load(xbase + (size_t)(s + 2) * 6291456 + goff);
    __syncthreads();    // [A] buf[cur^1] published; buf[cur] main reads done

    // epilogue: softmax over channels, DPP quad-max, pool write into buf[cur]
    float* pool2 = reinterpret_cast<float*>(&lds[cur][0]);
#pragma unroll
    for (int tl = 0; tl < 7; ++tl) {
      float e[4];
#pragma unroll
      for (int q = 0; q < 4; ++q) e[q] = __builtin_amdgcn_exp2f(acc[tl][q]);
      float sm = (e[0] + e[1]) + (e[2] + e[3]);
      sm += __shfl_xor(sm, 16, 64);
      sm += __shfl_xor(sm, 32, 64);
      float rs = __builtin_amdgcn_rcpf(sm);
      float pm[4];
#pragma unroll
      for (int q = 0; q < 4; ++q) pm[q] = e[q] * rs;
#pragma unroll
      for (int q = 0; q < 4; ++q) {
        pm[q] = dpp_max<0xB1>(pm[q]);   // wq xor1
        pm[q] = dpp_max<0x4E>(pm[q]);   // wq xor2
      }
      if (poolWr) {
        float4 val = {pm[0], pm[1], pm[2], pm[3]};
        *reinterpret_cast<float4*>(&pool2[poolIdx[tl]]) = val;
      }
    }
    __syncthreads();    // [B] pool published

    // tail: pair (tid, tid^1) split 16 slots 8/8, DPP pair-max, store
    if (tid < 224) {
      float m = pool2[tailBase];
#pragma unroll
      for (int s2 = 1; s2 < 8; ++s2)
        m = fmaxf(m, pool2[tailBase + s2 * 112]);
      m = dpp_max<0xB1>(m);     // combine lanes 2k,2k+1
      if (th == 0)
        out[(size_t)(n0 + 128 * s) * 2352 + outOff] = m;
    }
    __syncthreads();    // [C] pool reads done -> buf[cur] free for site s+2
  }
}

extern "C" void kernel_launch(void* const* d_in, const int* in_sizes, int n_in,
                              void* d_out, int out_size, void* d_ws, size_t ws_size,
                              hipStream_t stream) {
  const float* x = (const float*)d_in[0];
  const float* w = (const float*)d_in[1];
  const float* b = (const float*)d_in[2];
  float* out = (float*)d_out;
  int2* wsA = (int2*)d_ws;   // 7 windows * 64 lanes * 8 B = 3584 B
  (void)in_sizes; (void)n_in; (void)out_size; (void)ws_size;
  hipLaunchKernelGGL(wtrans, dim3(1), dim3(448), 0, stream, w, wsA);
  hipLaunchKernelGGL(conv_sm_pool, dim3(512 * 3 * 7 / 4), dim3(256), 0, stream,
                     x, wsA, b, out);
}

// Round 6
// 204.851 us; speedup vs baseline: 1.2937x; 1.2937x over previous
//
#include <hip/hip_runtime.h>
#include <hip/hip_fp16.h>

// Fused Conv3d(3->16, 3x3x3, VALID) + bias + channel softmax + maxpool(4,4,4)/4.
// x: [512,3,16,32,32] f32, w: [16,3,3,3,3] f32, b: [16] f32 -> out [512,16,3,7,7] f32
//
// R16: R15's 4-site prefetch spilled (WRITE_SIZE 16.6->187 MB = scratch) because
// prefetch registers stayed live across the fence-pinned MFMA loop. R16 keeps
// the amortization but with ZERO cross-main-loop register residency:
//  - 2 sites per block (n0, n0+256), BOTH staged up-front into buf0/buf1;
//    staging temps dead before the first MFMA. Two load batches pipeline ->
//    one site's HBM latency hidden; setup (wa/tvi/pbi/poolIdx/tail) paid once.
//  - pool buffer aliases buf[s] after site s's main loop (other buf untouched).
//  - log2(e) folded into weights+bias -> epilogue exp is raw v_exp_f32 (exp2).
// Main loop / epilogue otherwise identical to R14 (74.6 us): K=16 MFMA,
// 2 shift-copies, ds_read2_b32 gather, fence-pinned double buffer, DPP quad-max.

typedef _Float16 half4 __attribute__((ext_vector_type(4)));
typedef float f32x4 __attribute__((ext_vector_type(4)));
union H4 { int2 i; half4 h; };

template <int CTRL>
__device__ __forceinline__ float dpp_max(float x) {
  int xi = __builtin_bit_cast(int, x);
  int yi = __builtin_amdgcn_update_dpp(xi, xi, CTRL, 0xf, 0xf, false);
  return fmaxf(x, __builtin_bit_cast(float, yi));
}
// quad_perm ctrls: xor1 = [1,0,3,2] = 0xB1, xor2 = [2,3,0,1] = 0x4E

// Convert 17 floats -> copy0 (8 ints) + copy1 (8 shift-1-half ints), write both.
__device__ __forceinline__ void cvt_write(int* buf, int li,
    float4 f0, float4 f1, float4 f2, float4 f3, float ex) {
  int c[8];
  __half2 h;
  h = __float22half2_rn(make_float2(f0.x, f0.y)); c[0] = *reinterpret_cast<int*>(&h);
  h = __float22half2_rn(make_float2(f0.z, f0.w)); c[1] = *reinterpret_cast<int*>(&h);
  h = __float22half2_rn(make_float2(f1.x, f1.y)); c[2] = *reinterpret_cast<int*>(&h);
  h = __float22half2_rn(make_float2(f1.z, f1.w)); c[3] = *reinterpret_cast<int*>(&h);
  h = __float22half2_rn(make_float2(f2.x, f2.y)); c[4] = *reinterpret_cast<int*>(&h);
  h = __float22half2_rn(make_float2(f2.z, f2.w)); c[5] = *reinterpret_cast<int*>(&h);
  h = __float22half2_rn(make_float2(f3.x, f3.y)); c[6] = *reinterpret_cast<int*>(&h);
  h = __float22half2_rn(make_float2(f3.z, f3.w)); c[7] = *reinterpret_cast<int*>(&h);
  int eh = (int)__half_as_ushort(__float2half(ex));
  int s[8];
#pragma unroll
  for (int k = 0; k < 7; ++k) s[k] = __builtin_amdgcn_alignbit(c[k + 1], c[k], 16);
  s[7] = __builtin_amdgcn_alignbit(eh, c[7], 16);
  int4 w0; w0.x = c[0]; w0.y = c[1]; w0.z = c[2]; w0.w = c[3];
  int4 w1; w1.x = c[4]; w1.y = c[5]; w1.z = c[6]; w1.w = c[7];
  *reinterpret_cast<int4*>(&buf[li])     = w0;
  *reinterpret_cast<int4*>(&buf[li + 4]) = w1;
  int4 w2; w2.x = s[0]; w2.y = s[1]; w2.z = s[2]; w2.w = s[3];
  int4 w3; w3.x = s[4]; w3.y = s[5]; w3.z = s[6]; w3.w = s[7];
  *reinterpret_cast<int4*>(&buf[1736 + li])     = w2;
  *reinterpret_cast<int4*>(&buf[1736 + li + 4]) = w3;
}

// Frag-ready weights for K=16, pre-scaled by log2(e): wsA[v][lane] = 4 halves
// A[c=lane&15][k=16v+4g+j], tap G = 4v+g, kw = j; zero for G>=27 or kw==3.
__global__ void wtrans(const float* __restrict__ w, int2* __restrict__ wsA) {
  int t = threadIdx.x;            // 448 threads: v = t>>6, lane = t&63
  if (t >= 448) return;
  int v = t >> 6, l = t & 63;
  int c = l & 15, g = l >> 4;
  int G = 4 * v + g;
  unsigned hh[4];
  for (int j = 0; j < 4; ++j) {
    float val = (G < 27 && j < 3) ? w[c * 81 + G * 3 + j] * 1.44269504088896f
                                  : 0.0f;
    __half h = __float2half(val);
    hh[j] = (unsigned)__half_as_ushort(h);
  }
  int2 o;
  o.x = (int)(hh[0] | (hh[1] << 16));
  o.y = (int)(hh[2] | (hh[3] << 16));
  wsA[v * 64 + l] = o;
}

__global__ __launch_bounds__(256, 4) void conv_sm_pool(
    const float* __restrict__ x, const int2* __restrict__ wsA,
    const float* __restrict__ b, float* __restrict__ out) {
  // Two site buffers. Each: 2 shifted copies of the 3456-half stream
  // (copy1 = shift-1-half) at int offsets 0 and 1736. Rows unpadded.
  // Gather: half-window Q..Q+3 -> copy Q&1, int index Q>>1 via ds_read2_b32.
  // Pool buffer [dd*4+dh][pw][c] aliases buf[s] after site s's main loop.
  __shared__ int lds[2][3472];

  const int tid = threadIdx.x;
  const int blk = blockIdx.x;                 // 5376 blocks
  const int n0 = blk / 21, rr = blk % 21, pd = rr / 7, ph = rr % 7;

  const int lane = tid & 63;
  const int dd = tid >> 6;            // wave = one dd slice (0..3)
  const int l15 = lane & 15, g = lane >> 4;

  // ---- once-per-block setup ----
  H4 wa[7];
#pragma unroll
  for (int v = 0; v < 7; ++v) wa[v].i = wsA[v * 64 + lane];

  float4 b4 = *reinterpret_cast<const float4*>(b + 4 * g);
  f32x4 binit;
  binit[0] = b4.x * 1.44269504088896f;
  binit[1] = b4.y * 1.44269504088896f;
  binit[2] = b4.z * 1.44269504088896f;
  binit[3] = b4.w * 1.44269504088896f;

  // tap-group int offsets: T = cin*576 + kd*96 + kh*16 for G = 4v+g (clamped)
  int tvi[7];
#pragma unroll
  for (int v = 0; v < 7; ++v) {
    int G = 4 * v + g;
    if (G > 26) G = 26;
    int cin = G / 9, r = G % 9;
    tvi[v] = cin * 576 + (r / 3) * 96 + (r % 3) * 16;
  }

  // position bases: P = dd*192 + dh*32 + wp (halves); pbi = (P>>1)+(P&1)*1736
  // and pool-store indices (hoisted from the epilogue).
  int pbi[7], poolIdx[7];
#pragma unroll
  for (int tl = 0; tl < 7; ++tl) {
    int rem = tl * 16;
    int dh0 = rem / 28, rem28 = rem % 28;
    int bump = (rem28 + l15) >= 28 ? 1 : 0;
    int wp = rem28 + l15 - 28 * bump;
    int dh = dh0 + bump;
    int P = dd * 192 + dh * 32 + wp;
    pbi[tl] = (P >> 1) + (P & 1) * 1736;
    poolIdx[tl] = (((dd * 4 + dh) * 7 + (wp >> 2)) << 4) + 4 * g;
  }
  const bool poolWr = (l15 & 3) == 0;

  // staging geometry (tid<216): one (row,seg) per thread
  const int row = tid >> 1, seg = tid & 1;    // row = cin*36 + ld*6 + lh
  const int s_lh = row % 6, s_t2 = row / 6;
  const int s_ld = s_t2 % 6, s_cin = s_t2 / 6;
  const int goff = ((s_cin * 16 + s_ld) * 32 + s_lh) * 32 + seg * 16;
  const int li = row * 16 + seg * 8;
  const bool stager = (tid < 216);

  // tail geometry (tid<224)
  const int tIdx = tid >> 1, th = tid & 1;
  const int tc = tIdx / 7, tpw = tIdx % 7;
  const int tailBase = ((th * 8) * 7 + tpw) * 16 + tc;   // +112 per slot
  const size_t outOff = (size_t)(tc * 3 + pd) * 49 + (size_t)ph * 7 + tpw;

  const float* xbase = x + (size_t)n0 * 49152
                     + (size_t)(4 * pd) * 1024 + (size_t)(4 * ph) * 32;

  // ---- stage BOTH sites up-front; all temps dead before the main loops ----
  if (stager) {
    const float* s0 = xbase + goff;
    const float* s1 = xbase + (size_t)256 * 49152 + goff;   // site 1: n0+256
    float4 a0 = *reinterpret_cast<const float4*>(s0);
    float4 a1 = *reinterpret_cast<const float4*>(s0 + 4);
    float4 a2 = *reinterpret_cast<const float4*>(s0 + 8);
    float4 a3 = *reinterpret_cast<const float4*>(s0 + 12);
    float ax = s0[16];
    float4 c0 = *reinterpret_cast<const float4*>(s1);
    float4 c1 = *reinterpret_cast<const float4*>(s1 + 4);
    float4 c2 = *reinterpret_cast<const float4*>(s1 + 8);
    float4 c3 = *reinterpret_cast<const float4*>(s1 + 12);
    float cx = s1[16];
    cvt_write(&lds[0][0], li, a0, a1, a2, a3, ax);
    cvt_write(&lds[1][0], li, c0, c1, c2, c3, cx);
  }
  __syncthreads();

  // ---- 2 sites ----
#pragma unroll
  for (int s = 0; s < 2; ++s) {
    const int* Bp = &lds[s][0];

    f32x4 acc[7];
#pragma unroll
    for (int tl = 0; tl < 7; ++tl) acc[tl] = binit;

    // main: 7 K-windows x 7 N-tiles, double-buffered, fence-pinned
    H4 bfA[7], bfB[7];
#pragma unroll
    for (int tl = 0; tl < 7; ++tl) {
      const int* p = &Bp[pbi[tl] + tvi[0]];
      bfA[tl].i.x = p[0]; bfA[tl].i.y = p[1];
    }
    __builtin_amdgcn_sched_barrier(0);
#pragma unroll
    for (int vv = 0; vv < 3; ++vv) {
      const int v0 = 2 * vv, v1 = 2 * vv + 1, v2 = 2 * vv + 2;
#pragma unroll
      for (int tl = 0; tl < 7; ++tl) {
        const int* p = &Bp[pbi[tl] + tvi[v1]];
        bfB[tl].i.x = p[0]; bfB[tl].i.y = p[1];
      }
      __builtin_amdgcn_sched_barrier(0);
#pragma unroll
      for (int tl = 0; tl < 7; ++tl)
        acc[tl] = __builtin_amdgcn_mfma_f32_16x16x16f16(wa[v0].h, bfA[tl].h, acc[tl], 0, 0, 0);
      __builtin_amdgcn_sched_barrier(0);
#pragma unroll
      for (int tl = 0; tl < 7; ++tl) {
        const int* p = &Bp[pbi[tl] + tvi[v2]];
        bfA[tl].i.x = p[0]; bfA[tl].i.y = p[1];
      }
      __builtin_amdgcn_sched_barrier(0);
#pragma unroll
      for (int tl = 0; tl < 7; ++tl)
        acc[tl] = __builtin_amdgcn_mfma_f32_16x16x16f16(wa[v1].h, bfB[tl].h, acc[tl], 0, 0, 0);
      __builtin_amdgcn_sched_barrier(0);
    }
#pragma unroll
    for (int tl = 0; tl < 7; ++tl)
      acc[tl] = __builtin_amdgcn_mfma_f32_16x16x16f16(wa[6].h, bfA[tl].h, acc[tl], 0, 0, 0);

    __syncthreads();    // site s tile reads done -> buf[s] reusable as pool

    // epilogue: softmax over channels, DPP quad-max, pool write into buf[s]
    float* pool2 = reinterpret_cast<float*>(&lds[s][0]);
#pragma unroll
    for (int tl = 0; tl < 7; ++tl) {
      float e[4];
#pragma unroll
      for (int q = 0; q < 4; ++q) e[q] = __builtin_amdgcn_exp2f(acc[tl][q]);
      float sm = (e[0] + e[1]) + (e[2] + e[3]);
      sm += __shfl_xor(sm, 16, 64);
      sm += __shfl_xor(sm, 32, 64);
      float rs = __builtin_amdgcn_rcpf(sm);
      float pm[4];
#pragma unroll
      for (int q = 0; q < 4; ++q) pm[q] = e[q] * rs;
#pragma unroll
      for (int q = 0; q < 4; ++q) {
        pm[q] = dpp_max<0xB1>(pm[q]);   // wp xor1
        pm[q] = dpp_max<0x4E>(pm[q]);   // wp xor2
      }
      if (poolWr) {
        float4 val = {pm[0], pm[1], pm[2], pm[3]};
        *reinterpret_cast<float4*>(&pool2[poolIdx[tl]]) = val;
      }
    }
    __syncthreads();    // pool published

    // tail: pair (tid, tid^1) split 16 slots 8/8, DPP pair-max, store
    if (tid < 224) {
      float m = pool2[tailBase];
#pragma unroll
      for (int s2 = 1; s2 < 8; ++s2)
        m = fmaxf(m, pool2[tailBase + s2 * 112]);
      m = dpp_max<0xB1>(m);     // combine lanes 2k,2k+1
      if (th == 0)
        out[(size_t)(n0 + 256 * s) * 2352 + outOff] = m;
    }
    // no barrier needed: next site's main reads buf[1-s], untouched by pool/tail
  }
}

extern "C" void kernel_launch(void* const* d_in, const int* in_sizes, int n_in,
                              void* d_out, int out_size, void* d_ws, size_t ws_size,
                              hipStream_t stream) {
  const float* x = (const float*)d_in[0];
  const float* w = (const float*)d_in[1];
  const float* b = (const float*)d_in[2];
  float* out = (float*)d_out;
  int2* wsA = (int2*)d_ws;   // 7 windows * 64 lanes * 8 B = 3584 B
  (void)in_sizes; (void)n_in; (void)out_size; (void)ws_size;
  hipLaunchKernelGGL(wtrans, dim3(1), dim3(448), 0, stream, w, wsA);
  hipLaunchKernelGGL(conv_sm_pool, dim3(256 * 21), dim3(256), 0, stream,
                     x, wsA, b, out);
}